// Round 1
// baseline (309.411 us; speedup 1.0000x reference)
//
#include <hip/hip_runtime.h>

#define NTOK 1024
#define CD 128
#define SCALE 0.17677669529663687f  // 32^-0.5

// ---------------- Kernel 1: QKV projection ----------------
// qkv[b][n][o] = sum_c x[b][c][n] * Wp[o][c] + bp[o],  o in [0,384)
// x layout: (b, c, 32, 32) -> x[b*131072 + c*1024 + n]
__global__ __launch_bounds__(256) void k_proj(const float* __restrict__ x,
                                              const float* __restrict__ Wp,
                                              const float* __restrict__ bp,
                                              float* __restrict__ qkv) {
    __shared__ float As[64][132];
    __shared__ float Bs[64][132];
    const int t = threadIdx.x;
    const int rt = blockIdx.x;            // 256 row tiles of 64 rows (b,n)
    const int ot = blockIdx.y;            // 6 col tiles of 64 outputs
    const int b = rt >> 4;
    const int n0 = (rt & 15) << 6;
    for (int e = t; e < 64 * 128; e += 256) {
        int c = e >> 6, r = e & 63;                     // coalesced over n
        As[r][c] = x[b * (CD * NTOK) + c * NTOK + n0 + r];
    }
    for (int e = t; e < 64 * 128; e += 256) {
        int o = e >> 7, c = e & 127;                    // coalesced over c
        Bs[o][c] = Wp[(ot * 64 + o) * CD + c];
    }
    __syncthreads();
    const int ti = t >> 4;   // i-group 0..15  (rows ti+16u)
    const int to = t & 15;   // o fastest -> coalesced stores (cols to+16u)
    float acc[4][4] = {};
    for (int kq = 0; kq < 32; ++kq) {
        float4 a[4], bb[4];
        #pragma unroll
        for (int u = 0; u < 4; ++u) a[u]  = *(const float4*)&As[ti + 16*u][kq*4];
        #pragma unroll
        for (int u = 0; u < 4; ++u) bb[u] = *(const float4*)&Bs[to + 16*u][kq*4];
        #pragma unroll
        for (int iu = 0; iu < 4; ++iu)
            #pragma unroll
            for (int ou = 0; ou < 4; ++ou)
                acc[iu][ou] += a[iu].x*bb[ou].x + a[iu].y*bb[ou].y
                             + a[iu].z*bb[ou].z + a[iu].w*bb[ou].w;
    }
    #pragma unroll
    for (int iu = 0; iu < 4; ++iu) {
        const int n = n0 + ti + 16*iu;
        #pragma unroll
        for (int ou = 0; ou < 4; ++ou) {
            const int o = ot*64 + to + 16*ou;
            qkv[(b * NTOK + n) * 384 + o] = acc[iu][ou] + bp[o];
        }
    }
}

// ---------------- Kernel 2: fused attention ----------------
// Per block: batch b, i-tile of 32 rows. Loop over 32 j-tiles of 32.
// Phase A: s[i,j,h] = sum_d q[i,h,d]*k[j,h,d]; W = softmax over h (elementwise in i,j).
// Phase B: out[i, h*32+d] += sum_j W[i,j,h]*v[j,h,d].
// qkv col mapping: q: h*96+d, k: h*96+32+d, v: h*96+64+d   (f = h*32+d)
__global__ __launch_bounds__(256) void k_attn(const float* __restrict__ qkv,
                                              float* __restrict__ res) {
    __shared__ float qs[32][132];
    __shared__ float ks[32][132];
    __shared__ float vs[32][132];
    __shared__ float wt[32][4][33];   // [j][h][i]
    const int t = threadIdx.x;
    const int b = blockIdx.x;
    const int it = blockIdx.y;
    const int i0 = it * 32;
    for (int e = t; e < 32 * 128; e += 256) {
        int r = e >> 7, f = e & 127;
        qs[r][f] = qkv[(b * NTOK + i0 + r) * 384 + (f >> 5) * 96 + (f & 31)];
    }
    const int ti = t >> 4, tj = t & 15;           // phase A: 2i x 2j per thread
    const int bi = t & 31, bg = t >> 5;           // phase B: row bi, cols bg*16..+16
    const int bh = bg >> 1;
    float acc[16] = {};
    __syncthreads();
    for (int jt = 0; jt < 32; ++jt) {
        const int j0 = jt * 32;
        for (int e = t; e < 32 * 128; e += 256) {
            int r = e >> 7, f = e & 127;
            const float* p = &qkv[(b * NTOK + j0 + r) * 384 + (f >> 5) * 96 + (f & 31)];
            ks[r][f] = p[32];
            vs[r][f] = p[64];
        }
        __syncthreads();
        // ---- phase A: scores + softmax over heads ----
        float sv[4][4];   // [pair ii*2+jj][h]
        #pragma unroll
        for (int h = 0; h < 4; ++h) {
            float p00 = 0.f, p01 = 0.f, p10 = 0.f, p11 = 0.f;
            #pragma unroll
            for (int dq = 0; dq < 32; dq += 4) {
                const float4 qa = *(const float4*)&qs[ti*2+0][h*32+dq];
                const float4 qb = *(const float4*)&qs[ti*2+1][h*32+dq];
                const float4 ka = *(const float4*)&ks[tj*2+0][h*32+dq];
                const float4 kb = *(const float4*)&ks[tj*2+1][h*32+dq];
                p00 += qa.x*ka.x + qa.y*ka.y + qa.z*ka.z + qa.w*ka.w;
                p01 += qa.x*kb.x + qa.y*kb.y + qa.z*kb.z + qa.w*kb.w;
                p10 += qb.x*ka.x + qb.y*ka.y + qb.z*ka.z + qb.w*ka.w;
                p11 += qb.x*kb.x + qb.y*kb.y + qb.z*kb.z + qb.w*kb.w;
            }
            sv[0][h] = p00; sv[1][h] = p01; sv[2][h] = p10; sv[3][h] = p11;
        }
        #pragma unroll
        for (int pr = 0; pr < 4; ++pr) {
            const int ii = pr >> 1, jj = pr & 1;
            float s0 = sv[pr][0] * SCALE, s1 = sv[pr][1] * SCALE,
                  s2 = sv[pr][2] * SCALE, s3 = sv[pr][3] * SCALE;
            float m = fmaxf(fmaxf(s0, s1), fmaxf(s2, s3));
            float e0 = __expf(s0 - m), e1 = __expf(s1 - m),
                  e2 = __expf(s2 - m), e3 = __expf(s3 - m);
            float inv = 1.0f / (e0 + e1 + e2 + e3);
            float* w = &wt[tj*2+jj][0][ti*2+ii];
            w[0*33] = e0 * inv; w[1*33] = e1 * inv;
            w[2*33] = e2 * inv; w[3*33] = e3 * inv;
        }
        __syncthreads();
        // ---- phase B: accumulate W @ V ----
        #pragma unroll 4
        for (int jj = 0; jj < 32; ++jj) {
            const float w = wt[jj][bh][bi];
            const float4 v0 = *(const float4*)&vs[jj][bg*16 + 0];
            const float4 v1 = *(const float4*)&vs[jj][bg*16 + 4];
            const float4 v2 = *(const float4*)&vs[jj][bg*16 + 8];
            const float4 v3 = *(const float4*)&vs[jj][bg*16 + 12];
            acc[0]  += w*v0.x; acc[1]  += w*v0.y; acc[2]  += w*v0.z; acc[3]  += w*v0.w;
            acc[4]  += w*v1.x; acc[5]  += w*v1.y; acc[6]  += w*v1.z; acc[7]  += w*v1.w;
            acc[8]  += w*v2.x; acc[9]  += w*v2.y; acc[10] += w*v2.z; acc[11] += w*v2.w;
            acc[12] += w*v3.x; acc[13] += w*v3.y; acc[14] += w*v3.z; acc[15] += w*v3.w;
        }
        __syncthreads();
    }
    float* r = &res[(b * NTOK + i0 + bi) * CD + bg * 16];
    #pragma unroll
    for (int u = 0; u < 16; ++u) r[u] = acc[u];
}

// ---------------- Kernel 3: output projection + bias + residual ----------------
// out[b][o][n] = sum_k res[b][n][k]*Wo[o][k] + bo[o] + x[b][o][n]
__global__ __launch_bounds__(256) void k_out(const float* __restrict__ res,
                                             const float* __restrict__ Wo,
                                             const float* __restrict__ bo,
                                             const float* __restrict__ x,
                                             float* __restrict__ out) {
    __shared__ float As[64][132];
    __shared__ float Bs[64][132];
    const int t = threadIdx.x;
    const int rt = blockIdx.x;   // 256 tiles of 64 rows
    const int ot = blockIdx.y;   // 2 tiles of 64 cols
    const int b = rt >> 4;
    const int n0 = (rt & 15) << 6;
    for (int e = t; e < 64 * 128; e += 256) {
        int r = e >> 7, c = e & 127;
        As[r][c] = res[(b * NTOK + n0 + r) * CD + c];
    }
    for (int e = t; e < 64 * 128; e += 256) {
        int o = e >> 7, c = e & 127;
        Bs[o][c] = Wo[(ot * 64 + o) * CD + c];
    }
    __syncthreads();
    const int ti = t & 15;     // n fastest -> coalesced stores (out is n-contiguous)
    const int to = t >> 4;
    float acc[4][4] = {};
    for (int kq = 0; kq < 32; ++kq) {
        float4 a[4], bb[4];
        #pragma unroll
        for (int u = 0; u < 4; ++u) a[u]  = *(const float4*)&As[ti + 16*u][kq*4];
        #pragma unroll
        for (int u = 0; u < 4; ++u) bb[u] = *(const float4*)&Bs[to + 16*u][kq*4];
        #pragma unroll
        for (int iu = 0; iu < 4; ++iu)
            #pragma unroll
            for (int ou = 0; ou < 4; ++ou)
                acc[iu][ou] += a[iu].x*bb[ou].x + a[iu].y*bb[ou].y
                             + a[iu].z*bb[ou].z + a[iu].w*bb[ou].w;
    }
    #pragma unroll
    for (int ou = 0; ou < 4; ++ou) {
        const int o = ot*64 + to + 16*ou;
        #pragma unroll
        for (int iu = 0; iu < 4; ++iu) {
            const int n = n0 + ti + 16*iu;
            const int gi = b * (CD * NTOK) + o * NTOK + n;
            out[gi] = acc[iu][ou] + bo[o] + x[gi];
        }
    }
}

extern "C" void kernel_launch(void* const* d_in, const int* in_sizes, int n_in,
                              void* d_out, int out_size, void* d_ws, size_t ws_size,
                              hipStream_t stream) {
    const float* x  = (const float*)d_in[0];
    const float* Wp = (const float*)d_in[1];
    const float* bp = (const float*)d_in[2];
    const float* Wo = (const float*)d_in[3];
    const float* bo = (const float*)d_in[4];
    float* out = (float*)d_out;
    float* qkv = (float*)d_ws;                       // 16*1024*384 f32 = 25.2 MB
    float* res = qkv + 16 * 1024 * 384;              // 16*1024*128 f32 =  8.4 MB
    k_proj<<<dim3(256, 6), 256, 0, stream>>>(x, Wp, bp, qkv);
    k_attn<<<dim3(16, 32), 256, 0, stream>>>(qkv, res);
    k_out<<<dim3(256, 2), 256, 0, stream>>>(res, Wo, bo, x, out);
}

// Round 2
// 96.069 us; speedup vs baseline: 3.2207x; 3.2207x over previous
//
#include <hip/hip_runtime.h>

typedef short s8v __attribute__((ext_vector_type(8)));
typedef float f4v __attribute__((ext_vector_type(4)));

#define NTOK 1024
#define CD 128
// 32^-0.5 * log2(e): folded into q so scores are already in exp2 domain
#define QSCALE 0.25506953149031838f

__device__ __forceinline__ ushort f2bf(float x) {
    union { float f; unsigned u; } v; v.f = x;
    unsigned u = v.u + 0x7fff + ((v.u >> 16) & 1);
    return (ushort)(u >> 16);
}

// ---------------- Kernel 1: QKV projection (fp32 GEMM, bf16 outputs) ----------------
// qkv[b][n][o] = sum_c x[b][c][n]*Wp[o][c] + bp[o]; o = h*96 + kind*32 + d
// q (kind0) -> qb[b][n][h*32+d]  (scaled by QSCALE)
// k (kind1) -> kb[b][n][h*32+d]
// v (kind2) -> vtb[b][h*32+d][n] (transposed)
__global__ __launch_bounds__(256) void k_proj(const float* __restrict__ x,
                                              const float* __restrict__ Wp,
                                              const float* __restrict__ bp,
                                              ushort* __restrict__ qb,
                                              ushort* __restrict__ kb,
                                              ushort* __restrict__ vtb) {
    __shared__ float As[64][132];
    __shared__ float Bs[64][132];
    const int t = threadIdx.x;
    const int rt = blockIdx.x;            // 256 row tiles of 64 rows (b,n)
    const int ot = blockIdx.y;            // 6 col tiles of 64 outputs
    const int b = rt >> 4;
    const int n0 = (rt & 15) << 6;
    for (int e = t; e < 64 * 128; e += 256) {
        int c = e >> 6, r = e & 63;
        As[r][c] = x[b * (CD * NTOK) + c * NTOK + n0 + r];
    }
    for (int e = t; e < 64 * 128; e += 256) {
        int o = e >> 7, c = e & 127;
        Bs[o][c] = Wp[(ot * 64 + o) * CD + c];
    }
    __syncthreads();
    const int ti = t >> 4;
    const int to = t & 15;
    float acc[4][4] = {};
    for (int kq = 0; kq < 32; ++kq) {
        float4 a[4], bb[4];
        #pragma unroll
        for (int u = 0; u < 4; ++u) a[u]  = *(const float4*)&As[ti + 16*u][kq*4];
        #pragma unroll
        for (int u = 0; u < 4; ++u) bb[u] = *(const float4*)&Bs[to + 16*u][kq*4];
        #pragma unroll
        for (int iu = 0; iu < 4; ++iu)
            #pragma unroll
            for (int ou = 0; ou < 4; ++ou)
                acc[iu][ou] += a[iu].x*bb[ou].x + a[iu].y*bb[ou].y
                             + a[iu].z*bb[ou].z + a[iu].w*bb[ou].w;
    }
    #pragma unroll
    for (int iu = 0; iu < 4; ++iu) {
        const int n = n0 + ti + 16*iu;
        #pragma unroll
        for (int ou = 0; ou < 4; ++ou) {
            const int o = ot*64 + to + 16*ou;
            float val = acc[iu][ou] + bp[o];
            const int h = o / 96, rem = o % 96, kind = rem >> 5, d = rem & 31;
            const int f = h*32 + d;
            if (kind == 0)      qb[(b*NTOK + n)*CD + f] = f2bf(val * QSCALE);
            else if (kind == 1) kb[(b*NTOK + n)*CD + f] = f2bf(val);
            else                vtb[(b*CD + f)*NTOK + n] = f2bf(val);
        }
    }
}

// ---------------- Kernel 2: fused MFMA attention ----------------
// Grid: (b=16, it=16, js=2). Block = 4 waves; wave w owns i-rows [it*64+w*16, +16).
// Per 32-j tile: S^T[j][i] per head via mfma(Kfrag, Qfrag); softmax over h lane-local;
// W -> bf16 via wave-private LDS round-trip; PV via mfma(Wfrag, Vfrag).
__global__ __launch_bounds__(256, 2) void k_attn(const ushort* __restrict__ qb,
                                                 const ushort* __restrict__ kb,
                                                 const ushort* __restrict__ vtb,
                                                 float* __restrict__ res2) {
    __shared__ ushort kbuf[32 * 136];        // 32 j-rows x 128 f, stride 136 (272B)
    __shared__ ushort vbuf[128 * 40];        // 128 f-rows x 32 j, stride 40 (80B)
    __shared__ ushort wbuf[16 * 16 * 40];    // [wave*4+h][16 i][32 j], stride 40
    const int t = threadIdx.x;
    const int lane = t & 63;
    const int w = t >> 6;
    const int b = blockIdx.x;
    const int it = blockIdx.y;
    const int js = blockIdx.z;
    const int i0 = it * 64 + w * 16;
    const int li = lane & 15;
    const int lg = lane >> 4;

    // Q fragments, one per head (B-operand layout: n=i=li, k=d=lg*8+e)
    s8v qf[4];
    #pragma unroll
    for (int h = 0; h < 4; ++h)
        qf[h] = *(const s8v*)&qb[(b*NTOK + i0 + li)*CD + h*32 + lg*8];

    const f4v fz = {0.f, 0.f, 0.f, 0.f};
    f4v acc[4][2];
    #pragma unroll
    for (int h = 0; h < 4; ++h) { acc[h][0] = fz; acc[h][1] = fz; }

    const int j0 = js * 512;
    // staging: K rows (t>>4, +16), seg t&15; V rows (t>>2, +64), seg t&3
    s8v kst0, kst1, vst0, vst1;
    kst0 = *(const s8v*)&kb[(b*NTOK + j0 + (t>>4))*CD + (t&15)*8];
    kst1 = *(const s8v*)&kb[(b*NTOK + j0 + 16 + (t>>4))*CD + (t&15)*8];
    vst0 = *(const s8v*)&vtb[(b*CD + (t>>2))*NTOK + j0 + (t&3)*8];
    vst1 = *(const s8v*)&vtb[(b*CD + 64 + (t>>2))*NTOK + j0 + (t&3)*8];

    for (int jt = 0; jt < 16; ++jt) {
        __syncthreads();   // previous tile's LDS reads done
        *(s8v*)&kbuf[(t>>4)*136 + (t&15)*8]        = kst0;
        *(s8v*)&kbuf[((t>>4)+16)*136 + (t&15)*8]   = kst1;
        *(s8v*)&vbuf[(t>>2)*40 + (t&3)*8]          = vst0;
        *(s8v*)&vbuf[((t>>2)+64)*40 + (t&3)*8]     = vst1;
        if (jt < 15) {
            const int j1 = j0 + (jt+1)*32;
            kst0 = *(const s8v*)&kb[(b*NTOK + j1 + (t>>4))*CD + (t&15)*8];
            kst1 = *(const s8v*)&kb[(b*NTOK + j1 + 16 + (t>>4))*CD + (t&15)*8];
            vst0 = *(const s8v*)&vtb[(b*CD + (t>>2))*NTOK + j1 + (t&3)*8];
            vst1 = *(const s8v*)&vtb[(b*CD + 64 + (t>>2))*NTOK + j1 + (t&3)*8];
        }
        __syncthreads();   // staging visible

        // ---- S^T per head: D[j][i], lane holds (i=li, j=16*jh + lg*4 + r) ----
        f4v s[4][2];
        #pragma unroll
        for (int h = 0; h < 4; ++h) {
            #pragma unroll
            for (int jh = 0; jh < 2; ++jh) {
                s8v kf = *(const s8v*)&kbuf[(jh*16 + li)*136 + h*32 + lg*8];
                s[h][jh] = __builtin_amdgcn_mfma_f32_16x16x32_bf16(kf, qf[h], fz, 0, 0, 0);
            }
        }
        // ---- softmax over heads (lane-local, exp2 domain, no max-sub) ----
        #pragma unroll
        for (int jh = 0; jh < 2; ++jh) {
            #pragma unroll
            for (int r = 0; r < 4; ++r) {
                float e0 = __builtin_exp2f(s[0][jh][r]);
                float e1 = __builtin_exp2f(s[1][jh][r]);
                float e2 = __builtin_exp2f(s[2][jh][r]);
                float e3 = __builtin_exp2f(s[3][jh][r]);
                float inv = __builtin_amdgcn_rcpf(e0 + e1 + e2 + e3);
                s[0][jh][r] = e0 * inv;
                s[1][jh][r] = e1 * inv;
                s[2][jh][r] = e2 * inv;
                s[3][jh][r] = e3 * inv;
            }
        }
        // ---- per head: W -> bf16 A-frag via wave-private LDS, then PV ----
        #pragma unroll
        for (int h = 0; h < 4; ++h) {
            const int base = ((w<<2) + h) * 640;   // 16 rows * 40 ushorts
            uint2 d0, d1;
            d0.x = (unsigned)f2bf(s[h][0][0]) | ((unsigned)f2bf(s[h][0][1]) << 16);
            d0.y = (unsigned)f2bf(s[h][0][2]) | ((unsigned)f2bf(s[h][0][3]) << 16);
            d1.x = (unsigned)f2bf(s[h][1][0]) | ((unsigned)f2bf(s[h][1][1]) << 16);
            d1.y = (unsigned)f2bf(s[h][1][2]) | ((unsigned)f2bf(s[h][1][3]) << 16);
            *(uint2*)&wbuf[base + li*40 + lg*4]      = d0;   // j = lg*4..+3
            *(uint2*)&wbuf[base + li*40 + 16 + lg*4] = d1;   // j = 16+lg*4..+3
            s8v wf = *(const s8v*)&wbuf[base + li*40 + lg*8]; // A: (i=li, j=lg*8+e)
            s8v vf0 = *(const s8v*)&vbuf[(h*32 + li)*40 + lg*8];
            s8v vf1 = *(const s8v*)&vbuf[(h*32 + 16 + li)*40 + lg*8];
            acc[h][0] = __builtin_amdgcn_mfma_f32_16x16x32_bf16(wf, vf0, acc[h][0], 0, 0, 0);
            acc[h][1] = __builtin_amdgcn_mfma_f32_16x16x32_bf16(wf, vf1, acc[h][1], 0, 0, 0);
        }
    }
    // ---- epilogue: D[i][d], lane holds (d = dh*16+li, i = lg*4+r) ----
    #pragma unroll
    for (int h = 0; h < 4; ++h)
        #pragma unroll
        for (int dh = 0; dh < 2; ++dh)
            #pragma unroll
            for (int r = 0; r < 4; ++r) {
                const int i = i0 + lg*4 + r;
                const int f = h*32 + dh*16 + li;
                res2[js*(16*NTOK*CD) + (b*NTOK + i)*CD + f] = acc[h][dh][r];
            }
}

// ---------------- Kernel 3: output projection + bias + residual ----------------
__global__ __launch_bounds__(256) void k_out(const float* __restrict__ res2,
                                             const float* __restrict__ Wo,
                                             const float* __restrict__ bo,
                                             const float* __restrict__ x,
                                             float* __restrict__ out) {
    __shared__ float As[64][132];
    __shared__ float Bs[64][132];
    const int t = threadIdx.x;
    const int rt = blockIdx.x;
    const int ot = blockIdx.y;
    const int b = rt >> 4;
    const int n0 = (rt & 15) << 6;
    for (int e = t; e < 64 * 128; e += 256) {
        int r = e >> 7, c = e & 127;
        const int idx = (b * NTOK + n0 + r) * CD + c;
        As[r][c] = res2[idx] + res2[idx + 16*NTOK*CD];
    }
    for (int e = t; e < 64 * 128; e += 256) {
        int o = e >> 7, c = e & 127;
        Bs[o][c] = Wo[(ot * 64 + o) * CD + c];
    }
    __syncthreads();
    const int ti = t & 15;
    const int to = t >> 4;
    float acc[4][4] = {};
    for (int kq = 0; kq < 32; ++kq) {
        float4 a[4], bb[4];
        #pragma unroll
        for (int u = 0; u < 4; ++u) a[u]  = *(const float4*)&As[ti + 16*u][kq*4];
        #pragma unroll
        for (int u = 0; u < 4; ++u) bb[u] = *(const float4*)&Bs[to + 16*u][kq*4];
        #pragma unroll
        for (int iu = 0; iu < 4; ++iu)
            #pragma unroll
            for (int ou = 0; ou < 4; ++ou)
                acc[iu][ou] += a[iu].x*bb[ou].x + a[iu].y*bb[ou].y
                             + a[iu].z*bb[ou].z + a[iu].w*bb[ou].w;
    }
    #pragma unroll
    for (int ou = 0; ou < 4; ++ou) {
        const int o = ot*64 + to + 16*ou;
        #pragma unroll
        for (int iu = 0; iu < 4; ++iu) {
            const int n = n0 + ti + 16*iu;
            const int gi = b * (CD * NTOK) + o * NTOK + n;
            out[gi] = acc[iu][ou] + bo[o] + x[gi];
        }
    }
}

extern "C" void kernel_launch(void* const* d_in, const int* in_sizes, int n_in,
                              void* d_out, int out_size, void* d_ws, size_t ws_size,
                              hipStream_t stream) {
    const float* x  = (const float*)d_in[0];
    const float* Wp = (const float*)d_in[1];
    const float* bp = (const float*)d_in[2];
    const float* Wo = (const float*)d_in[3];
    const float* bo = (const float*)d_in[4];
    float* out = (float*)d_out;
    ushort* qbw = (ushort*)d_ws;                 // 16*1024*128 bf16 = 4 MB
    ushort* kbw = qbw + 16*1024*128;             // 4 MB
    ushort* vtb = kbw + 16*1024*128;             // 4 MB
    float* res2 = (float*)(vtb + 16*1024*128);   // 2 * 8.4 MB partials
    k_proj<<<dim3(256, 6), 256, 0, stream>>>(x, Wp, bp, qbw, kbw, vtb);
    k_attn<<<dim3(16, 16, 2), 256, 0, stream>>>(qbw, kbw, vtb, res2);
    k_out<<<dim3(256, 2), 256, 0, stream>>>(res2, Wo, bo, x, out);
}

// Round 3
// 62.827 us; speedup vs baseline: 4.9248x; 1.5291x over previous
//
#include <hip/hip_runtime.h>

typedef short s8v __attribute__((ext_vector_type(8)));
typedef float f4v __attribute__((ext_vector_type(4)));

#define NTOK 1024
#define CD 128
#define QSCALE 0.25506953149031838f  // 32^-0.5 * log2(e)

__device__ __forceinline__ ushort f2bf(float x) {
    union { float f; unsigned u; } v; v.f = x;
    unsigned u = v.u + 0x7fff + ((v.u >> 16) & 1);
    return (ushort)(u >> 16);
}
__device__ __forceinline__ float bf2f(ushort x) {
    union { unsigned u; float f; } v; v.u = ((unsigned)x) << 16;
    return v.f;
}
__device__ __forceinline__ void gl_lds16(const ushort* g, ushort* l) {
    __builtin_amdgcn_global_load_lds(
        (const __attribute__((address_space(1))) unsigned int*)(g),
        (__attribute__((address_space(3))) unsigned int*)(l), 16, 0, 0);
}

// ---------------- Kernel 0: transpose/convert x -> xt (swizzled bf16), prep weights ----
// blocks [0,256): b = bx>>4, n0 = (bx&15)*64: 64n x 128c transpose tile
// blocks [256,260): weight prep: kind 0=Wq,1=Wk,2=Wv,3=Wo -> wpre (swizzled bf16)
// swizzle convention: element (row, c) stored at row*128 + ((c>>3)^(row&7))*8 + (c&7)
__global__ __launch_bounds__(256) void k_pre(const float* __restrict__ x,
                                             const float* __restrict__ Wp,
                                             const float* __restrict__ Wo,
                                             ushort* __restrict__ xt,
                                             ushort* __restrict__ wpre) {
    const int t = threadIdx.x;
    const int bx = blockIdx.x;
    if (bx < 256) {
        __shared__ ushort tile[128 * 68];   // [c][n], stride 68 (136B, 8B-aligned)
        const int b = bx >> 4;
        const int n0 = (bx & 15) << 6;
        #pragma unroll
        for (int p = 0; p < 8; ++p) {
            const int c = p * 16 + (t >> 4);
            const int n4 = t & 15;
            const float4 v = *(const float4*)&x[(b * CD + c) * NTOK + n0 + n4 * 4];
            ushort4 o;
            o.x = f2bf(v.x); o.y = f2bf(v.y); o.z = f2bf(v.z); o.w = f2bf(v.w);
            *(ushort4*)&tile[c * 68 + n4 * 4] = o;
        }
        __syncthreads();
        #pragma unroll
        for (int p = 0; p < 4; ++p) {
            const int nl = t >> 2;
            const int g = (t & 3) + p * 4;
            s8v tmp;
            #pragma unroll
            for (int e = 0; e < 8; ++e) tmp[e] = (short)tile[(g * 8 + e) * 68 + nl];
            const int n = n0 + nl;
            *(s8v*)&xt[(b * NTOK + n) * CD + ((g ^ (nl & 7)) * 8)] = tmp;
        }
    } else {
        const int kind = bx - 256;   // 0=q,1=k,2=v,3=Wo
        ushort* dst = wpre + kind * (CD * CD);
        for (int e = t * 4; e < CD * CD; e += 1024) {
            const int f = e >> 7, c = e & 127;
            const float* src;
            if (kind == 3) src = &Wo[f * CD + c];
            else           src = &Wp[((f >> 5) * 96 + kind * 32 + (f & 31)) * CD + c];
            const float4 v = *(const float4*)src;
            ushort4 o;
            o.x = f2bf(v.x); o.y = f2bf(v.y); o.z = f2bf(v.z); o.w = f2bf(v.w);
            *(ushort4*)&dst[f * CD + (((c >> 3) ^ (f & 7)) * 8) + (c & 7)] = o;
        }
    }
}

// ---------------- Kernel 1: QKV projection, bf16 MFMA ----------------
// grid.x = 768: [0,256) q, [256,512) k, [512,768) v. BM=128 (A rows), BN=64 (B rows), K=128.
// q/k: A = xt tile (rows=(b,n)), B = Wq/Wk 64-row chunk; D[m=n][n=f] -> qb/kb[(b,n)][f]
// v:   A = Wv (128 f rows),      B = xt 64-row chunk;  D[m=f][n=n]  -> vtb[(b,f)][n]
__global__ __launch_bounds__(256) void k_proj(const ushort* __restrict__ xt,
                                              const ushort* __restrict__ wpre,
                                              const float* __restrict__ bp,
                                              ushort* __restrict__ qb,
                                              ushort* __restrict__ kb,
                                              ushort* __restrict__ vtb) {
    __shared__ ushort Abuf[128 * 128];
    __shared__ ushort Bbuf[64 * 128];
    const int t = threadIdx.x;
    const int lane = t & 63;
    const int w = t >> 6;
    const int li = lane & 15;
    const int lg = lane >> 4;
    const int bx = blockIdx.x;
    const int kind = bx >> 8;
    const int idx = bx & 255;

    const ushort* Asrc;
    const ushort* Bsrc;
    if (kind < 2) {
        Asrc = xt + (idx >> 1) * 128 * CD;
        Bsrc = wpre + kind * (CD * CD) + (idx & 1) * 64 * CD;
    } else {
        Asrc = wpre + 2 * (CD * CD);
        Bsrc = xt + idx * 64 * CD;
    }
    {
        const ushort* ga = Asrc + w * 4096;
        ushort* la = Abuf + w * 4096;
        #pragma unroll
        for (int i = 0; i < 8; ++i) gl_lds16(ga + i * 512 + lane * 8, la + i * 512);
        const ushort* gb = Bsrc + w * 2048;
        ushort* lb = Bbuf + w * 2048;
        #pragma unroll
        for (int i = 0; i < 4; ++i) gl_lds16(gb + i * 512 + lane * 8, lb + i * 512);
    }
    __syncthreads();

    const f4v fz = {0.f, 0.f, 0.f, 0.f};
    f4v acc[2][4];
    #pragma unroll
    for (int mf = 0; mf < 2; ++mf)
        #pragma unroll
        for (int nf = 0; nf < 4; ++nf) acc[mf][nf] = fz;
    const int m_base = w * 32;
    #pragma unroll
    for (int kk = 0; kk < 4; ++kk) {
        s8v a[2], bb[4];
        #pragma unroll
        for (int mf = 0; mf < 2; ++mf) {
            const int row = m_base + mf * 16 + li;
            a[mf] = *(const s8v*)&Abuf[row * CD + (((kk * 4 + lg) ^ (row & 7)) * 8)];
        }
        #pragma unroll
        for (int nf = 0; nf < 4; ++nf) {
            const int row = nf * 16 + li;
            bb[nf] = *(const s8v*)&Bbuf[row * CD + (((kk * 4 + lg) ^ (row & 7)) * 8)];
        }
        #pragma unroll
        for (int mf = 0; mf < 2; ++mf)
            #pragma unroll
            for (int nf = 0; nf < 4; ++nf)
                acc[mf][nf] = __builtin_amdgcn_mfma_f32_16x16x32_bf16(a[mf], bb[nf], acc[mf][nf], 0, 0, 0);
    }

    if (kind < 2) {
        ushort* dst = (kind == 0) ? qb : kb;
        const int m0 = (idx >> 1) * 128;
        const int f0 = (idx & 1) * 64;
        #pragma unroll
        for (int mf = 0; mf < 2; ++mf)
            #pragma unroll
            for (int nf = 0; nf < 4; ++nf) {
                const int f = f0 + nf * 16 + li;
                const int o = (f >> 5) * 96 + kind * 32 + (f & 31);
                const float bias = bp[o];
                #pragma unroll
                for (int r = 0; r < 4; ++r) {
                    const int row = m0 + m_base + mf * 16 + lg * 4 + r;
                    float v = acc[mf][nf][r] + bias;
                    if (kind == 0) v *= QSCALE;
                    dst[row * CD + f] = f2bf(v);
                }
            }
    } else {
        const int n0g = idx * 64;
        const int b = n0g >> 10;
        const int nl0 = n0g & 1023;
        #pragma unroll
        for (int mf = 0; mf < 2; ++mf)
            #pragma unroll
            for (int r = 0; r < 4; ++r) {
                const int f = m_base + mf * 16 + lg * 4 + r;
                const int o = (f >> 5) * 96 + 64 + (f & 31);
                const float bias = bp[o];
                #pragma unroll
                for (int nf = 0; nf < 4; ++nf) {
                    const int n = nl0 + nf * 16 + li;
                    vtb[(b * CD + f) * NTOK + n] = f2bf(acc[mf][nf][r] + bias);
                }
            }
    }
}

// ---------------- Kernel 2: fused MFMA attention ----------------
// Grid: (b=16, it=16, js=4). Block = 4 waves; wave w owns i-rows [it*64+w*16, +16).
__global__ __launch_bounds__(256) void k_attn(const ushort* __restrict__ qb,
                                              const ushort* __restrict__ kb,
                                              const ushort* __restrict__ vtb,
                                              ushort* __restrict__ res4) {
    __shared__ ushort kbuf[32 * 136];
    __shared__ ushort vbuf[128 * 40];
    __shared__ ushort wbuf[16 * 16 * 40];
    const int t = threadIdx.x;
    const int lane = t & 63;
    const int w = t >> 6;
    const int b = blockIdx.x;
    const int it = blockIdx.y;
    const int js = blockIdx.z;
    const int i0 = it * 64 + w * 16;
    const int li = lane & 15;
    const int lg = lane >> 4;

    s8v qf[4];
    #pragma unroll
    for (int h = 0; h < 4; ++h)
        qf[h] = *(const s8v*)&qb[(b*NTOK + i0 + li)*CD + h*32 + lg*8];

    const f4v fz = {0.f, 0.f, 0.f, 0.f};
    f4v acc[4][2];
    #pragma unroll
    for (int h = 0; h < 4; ++h) { acc[h][0] = fz; acc[h][1] = fz; }

    const int j0 = js * 256;
    s8v kst0, kst1, vst0, vst1;
    kst0 = *(const s8v*)&kb[(b*NTOK + j0 + (t>>4))*CD + (t&15)*8];
    kst1 = *(const s8v*)&kb[(b*NTOK + j0 + 16 + (t>>4))*CD + (t&15)*8];
    vst0 = *(const s8v*)&vtb[(b*CD + (t>>2))*NTOK + j0 + (t&3)*8];
    vst1 = *(const s8v*)&vtb[(b*CD + 64 + (t>>2))*NTOK + j0 + (t&3)*8];

    for (int jt = 0; jt < 8; ++jt) {
        __syncthreads();
        *(s8v*)&kbuf[(t>>4)*136 + (t&15)*8]        = kst0;
        *(s8v*)&kbuf[((t>>4)+16)*136 + (t&15)*8]   = kst1;
        *(s8v*)&vbuf[(t>>2)*40 + (t&3)*8]          = vst0;
        *(s8v*)&vbuf[((t>>2)+64)*40 + (t&3)*8]     = vst1;
        if (jt < 7) {
            const int j1 = j0 + (jt+1)*32;
            kst0 = *(const s8v*)&kb[(b*NTOK + j1 + (t>>4))*CD + (t&15)*8];
            kst1 = *(const s8v*)&kb[(b*NTOK + j1 + 16 + (t>>4))*CD + (t&15)*8];
            vst0 = *(const s8v*)&vtb[(b*CD + (t>>2))*NTOK + j1 + (t&3)*8];
            vst1 = *(const s8v*)&vtb[(b*CD + 64 + (t>>2))*NTOK + j1 + (t&3)*8];
        }
        __syncthreads();

        f4v s[4][2];
        #pragma unroll
        for (int h = 0; h < 4; ++h) {
            #pragma unroll
            for (int jh = 0; jh < 2; ++jh) {
                s8v kf = *(const s8v*)&kbuf[(jh*16 + li)*136 + h*32 + lg*8];
                s[h][jh] = __builtin_amdgcn_mfma_f32_16x16x32_bf16(kf, qf[h], fz, 0, 0, 0);
            }
        }
        #pragma unroll
        for (int jh = 0; jh < 2; ++jh) {
            #pragma unroll
            for (int r = 0; r < 4; ++r) {
                float e0 = __builtin_exp2f(s[0][jh][r]);
                float e1 = __builtin_exp2f(s[1][jh][r]);
                float e2 = __builtin_exp2f(s[2][jh][r]);
                float e3 = __builtin_exp2f(s[3][jh][r]);
                float inv = __builtin_amdgcn_rcpf(e0 + e1 + e2 + e3);
                s[0][jh][r] = e0 * inv;
                s[1][jh][r] = e1 * inv;
                s[2][jh][r] = e2 * inv;
                s[3][jh][r] = e3 * inv;
            }
        }
        #pragma unroll
        for (int h = 0; h < 4; ++h) {
            const int base = ((w<<2) + h) * 640;
            uint2 d0, d1;
            d0.x = (unsigned)f2bf(s[h][0][0]) | ((unsigned)f2bf(s[h][0][1]) << 16);
            d0.y = (unsigned)f2bf(s[h][0][2]) | ((unsigned)f2bf(s[h][0][3]) << 16);
            d1.x = (unsigned)f2bf(s[h][1][0]) | ((unsigned)f2bf(s[h][1][1]) << 16);
            d1.y = (unsigned)f2bf(s[h][1][2]) | ((unsigned)f2bf(s[h][1][3]) << 16);
            *(uint2*)&wbuf[base + li*40 + lg*4]      = d0;
            *(uint2*)&wbuf[base + li*40 + 16 + lg*4] = d1;
            s8v wf = *(const s8v*)&wbuf[base + li*40 + lg*8];
            s8v vf0 = *(const s8v*)&vbuf[(h*32 + li)*40 + lg*8];
            s8v vf1 = *(const s8v*)&vbuf[(h*32 + 16 + li)*40 + lg*8];
            acc[h][0] = __builtin_amdgcn_mfma_f32_16x16x32_bf16(wf, vf0, acc[h][0], 0, 0, 0);
            acc[h][1] = __builtin_amdgcn_mfma_f32_16x16x32_bf16(wf, vf1, acc[h][1], 0, 0, 0);
        }
    }
    #pragma unroll
    for (int h = 0; h < 4; ++h)
        #pragma unroll
        for (int dh = 0; dh < 2; ++dh)
            #pragma unroll
            for (int r = 0; r < 4; ++r) {
                const int i = i0 + lg*4 + r;
                const int f = h*32 + dh*16 + li;
                res4[js*(16*NTOK*CD) + (b*NTOK + i)*CD + f] = f2bf(acc[h][dh][r]);
            }
}

// ---------------- Kernel 3: output projection + bias + residual, bf16 MFMA ----------------
// A = Wo (128 o rows), B = sum of 4 res4 partials (64 n rows) -> D[m=o][n=n] (coalesced out)
__global__ __launch_bounds__(256) void k_out(const ushort* __restrict__ wpre,
                                             const ushort* __restrict__ res4,
                                             const float* __restrict__ bo,
                                             const float* __restrict__ x,
                                             float* __restrict__ out) {
    __shared__ ushort Abuf[128 * 128];
    __shared__ ushort Bbuf[64 * 128];
    const int t = threadIdx.x;
    const int lane = t & 63;
    const int w = t >> 6;
    const int li = lane & 15;
    const int lg = lane >> 4;
    const int idx = blockIdx.x;          // 256 chunks of 64 (b,n) rows
    const int n0g = idx * 64;
    const int b = n0g >> 10;
    {
        const ushort* ga = wpre + 3 * (CD * CD) + w * 4096;
        ushort* la = Abuf + w * 4096;
        #pragma unroll
        for (int i = 0; i < 8; ++i) gl_lds16(ga + i * 512 + lane * 8, la + i * 512);
    }
    for (int u = t; u < 64 * 16; u += 256) {
        const int rl = u >> 4, g = u & 15;
        const ushort* p = &res4[(n0g + rl) * CD + g * 8];
        s8v p0 = *(const s8v*)(p);
        s8v p1 = *(const s8v*)(p + 16*NTOK*CD);
        s8v p2 = *(const s8v*)(p + 32*NTOK*CD);
        s8v p3 = *(const s8v*)(p + 48*NTOK*CD);
        s8v sm;
        #pragma unroll
        for (int e = 0; e < 8; ++e)
            sm[e] = (short)f2bf(bf2f((ushort)p0[e]) + bf2f((ushort)p1[e])
                              + bf2f((ushort)p2[e]) + bf2f((ushort)p3[e]));
        *(s8v*)&Bbuf[rl * CD + ((g ^ (rl & 7)) * 8)] = sm;
    }
    __syncthreads();

    const f4v fz = {0.f, 0.f, 0.f, 0.f};
    f4v acc[2][4];
    #pragma unroll
    for (int mf = 0; mf < 2; ++mf)
        #pragma unroll
        for (int nf = 0; nf < 4; ++nf) acc[mf][nf] = fz;
    const int m_base = w * 32;
    #pragma unroll
    for (int kk = 0; kk < 4; ++kk) {
        s8v a[2], bb[4];
        #pragma unroll
        for (int mf = 0; mf < 2; ++mf) {
            const int row = m_base + mf * 16 + li;
            a[mf] = *(const s8v*)&Abuf[row * CD + (((kk * 4 + lg) ^ (row & 7)) * 8)];
        }
        #pragma unroll
        for (int nf = 0; nf < 4; ++nf) {
            const int row = nf * 16 + li;
            bb[nf] = *(const s8v*)&Bbuf[row * CD + (((kk * 4 + lg) ^ (row & 7)) * 8)];
        }
        #pragma unroll
        for (int mf = 0; mf < 2; ++mf)
            #pragma unroll
            for (int nf = 0; nf < 4; ++nf)
                acc[mf][nf] = __builtin_amdgcn_mfma_f32_16x16x32_bf16(a[mf], bb[nf], acc[mf][nf], 0, 0, 0);
    }
    const int nl0 = n0g & 1023;
    #pragma unroll
    for (int mf = 0; mf < 2; ++mf)
        #pragma unroll
        for (int r = 0; r < 4; ++r) {
            const int o = m_base + mf * 16 + lg * 4 + r;
            const float bias = bo[o];
            #pragma unroll
            for (int nf = 0; nf < 4; ++nf) {
                const int n = nl0 + nf * 16 + li;
                const int gi = (b * CD + o) * NTOK + n;
                out[gi] = acc[mf][nf][r] + bias + x[gi];
            }
        }
}

extern "C" void kernel_launch(void* const* d_in, const int* in_sizes, int n_in,
                              void* d_out, int out_size, void* d_ws, size_t ws_size,
                              hipStream_t stream) {
    const float* x  = (const float*)d_in[0];
    const float* Wp = (const float*)d_in[1];
    const float* bp = (const float*)d_in[2];
    const float* Wo = (const float*)d_in[3];
    const float* bo = (const float*)d_in[4];
    float* out = (float*)d_out;
    ushort* xt   = (ushort*)d_ws;                 // 4 MB
    ushort* wpre = xt + 16*1024*128;              // 128 KB (4 matrices)
    ushort* qbw  = wpre + 4*128*128;              // 4 MB
    ushort* kbw  = qbw + 16*1024*128;             // 4 MB
    ushort* vtb  = kbw + 16*1024*128;             // 4 MB
    ushort* res4 = vtb + 16*1024*128;             // 16.8 MB (4 partials)
    k_pre <<<260, 256, 0, stream>>>(x, Wp, Wo, xt, wpre);
    k_proj<<<768, 256, 0, stream>>>(xt, wpre, bp, qbw, kbw, vtb);
    k_attn<<<dim3(16, 16, 4), 256, 0, stream>>>(qbw, kbw, vtb, res4);
    k_out <<<256, 256, 0, stream>>>(wpre, res4, bo, x, out);
}